// Round 1
// baseline (1209.464 us; speedup 1.0000x reference)
//
#include <hip/hip_runtime.h>
#include <hip/hip_bf16.h>
#include <math.h>

// Problem constants (from reference)
#define A_AG   3
#define Bq     4096
#define Nn     64
#define FEAT   32
#define Hh     32
#define Rr     6
#define E_PER  1536
#define NACT   16

// ---------------------------------------------------------------------------
// Kernel 1: build per-(dst,rel) norms + dst-sorted CSR edge list into d_ws.
// Edge structure is shared across all graphs/agents -> do this once per launch.
// ws layout: [0 .. 512) row_start (65 ints, padded), [512 ..) int2 entries
//   entry.x = src | (rel << 8);  entry.y = bits of norm (1/cnt(dst,rel))
// ---------------------------------------------------------------------------
__global__ void prep_edges(const int* __restrict__ esrc,
                           const int* __restrict__ edst,
                           const int* __restrict__ erel,
                           int* __restrict__ row_start,
                           int2* __restrict__ entries) {
    __shared__ int cnt_dr[Nn * Rr];
    __shared__ int cnt_d[Nn];
    __shared__ int rs[Nn + 1];
    const int t = threadIdx.x;

    for (int i = t; i < Nn * Rr; i += 256) cnt_dr[i] = 0;
    if (t < Nn) cnt_d[t] = 0;
    __syncthreads();

    for (int e = t; e < E_PER; e += 256) {
        int d = edst[e], r = erel[e];
        atomicAdd(&cnt_dr[d * Rr + r], 1);
        atomicAdd(&cnt_d[d], 1);
    }
    __syncthreads();

    if (t == 0) {
        int s = 0;
        for (int d = 0; d < Nn; ++d) { rs[d] = s; s += cnt_d[d]; }
        rs[Nn] = s;
    }
    __syncthreads();

    if (t < Nn) {
        const int d = t;
        int pos = rs[d];
        for (int e = 0; e < E_PER; ++e) {
            if (edst[e] == d) {
                int r = erel[e];
                float norm = 1.0f / (float)cnt_dr[d * Rr + r];
                int2 en;
                en.x = (esrc[e] & 0xff) | (r << 8);
                en.y = __float_as_int(norm);
                entries[pos++] = en;
            }
        }
    }
    if (t < Nn + 1) row_start[t] = rs[t];
}

// ---------------------------------------------------------------------------
// Kernel 2: one workgroup per (graph b, agent a).
//   Phase 1: 7 transforms X@W (6 relations + root) -> LDS (stride 33, no bank
//            conflicts). Thread n keeps X row in 32 VGPRs; weights are
//            wave-uniform (readfirstlane'd col base) -> scalar loads.
//   Phase 2: CSR edge aggregation per dst (no atomics), + root + bias, ReLU,
//            running max for the pool.
//   Phase 3: max-pool reduce, build critic input, 64->32 leaky, 32->16,
//            Q-select by argmax(actions[a][b]).
// ---------------------------------------------------------------------------
__global__ __launch_bounds__(256) void critic_kernel(
    const float* __restrict__ unary,   // [A,B,N,FEAT]
    const float* __restrict__ actions, // [A,B,NACT]
    const float* __restrict__ w_rel,   // [R,FEAT,H]
    const float* __restrict__ w_root,  // [FEAT,H]
    const float* __restrict__ b_gnn,   // [H]
    const float* __restrict__ w1,      // [A,64,H]
    const float* __restrict__ b1,      // [A,H]
    const float* __restrict__ w2,      // [A,H,NACT]
    const float* __restrict__ b2,      // [A,NACT]
    const int*  __restrict__ row_start,
    const int2* __restrict__ entries,
    float* __restrict__ out)           // [A,B,1]
{
    const int b = blockIdx.x;
    const int a = blockIdx.y;
    const int t = threadIdx.x;

    __shared__ float ht[7][Nn * 33];   // transformed features, stride 33
    __shared__ float pmax[8][32];
    __shared__ float cin[64];          // critic input: pooled(32) ++ others(32)
    __shared__ float mid[32];
    __shared__ float allq[16];

    // ---- Phase 1: transforms -------------------------------------------
    const int n   = t & 63;            // node row this thread owns
    const int rep = t >> 6;            // wave id: which 8 output columns

    // X row -> registers (direct global; all 4 waves hit same 8KB -> L1)
    const float* Xrow = unary + (((size_t)a * Bq + b) * Nn + n) * FEAT;
    float xr[32];
    #pragma unroll
    for (int j = 0; j < 8; ++j) {
        float4 v = *(const float4*)(Xrow + 4 * j);
        xr[4 * j + 0] = v.x; xr[4 * j + 1] = v.y;
        xr[4 * j + 2] = v.z; xr[4 * j + 3] = v.w;
    }

    const int h0 = __builtin_amdgcn_readfirstlane(rep << 3);  // wave-uniform

    for (int m = 0; m < 7; ++m) {
        const float* wm = (m < 6) ? (w_rel + m * FEAT * Hh) : w_root;
        float acc[8] = {0.f, 0.f, 0.f, 0.f, 0.f, 0.f, 0.f, 0.f};
        #pragma unroll
        for (int k = 0; k < 32; ++k) {
            const float xv = xr[k];
            #pragma unroll
            for (int j = 0; j < 8; ++j)
                acc[j] = fmaf(xv, wm[k * Hh + h0 + j], acc[j]);
        }
        #pragma unroll
        for (int j = 0; j < 8; ++j)
            ht[m][n * 33 + h0 + j] = acc[j];
    }
    __syncthreads();

    // ---- Phase 2: edge aggregation + ReLU + running max -----------------
    const int h    = t & 31;
    const int slot = t >> 5;           // 8 groups of 8 dst nodes each
    const float bg = b_gnn[h];
    float lmax = -INFINITY;
    #pragma unroll
    for (int i = 0; i < 8; ++i) {
        const int d = slot * 8 + i;
        const int e0 = row_start[d], e1 = row_start[d + 1];
        float acc = 0.f;
        for (int e = e0; e < e1; ++e) {
            const int2 en = entries[e];
            const int src = en.x & 0xff;
            const int rel = en.x >> 8;
            const float norm = __int_as_float(en.y);
            acc = fmaf(norm, ht[rel][src * 33 + h], acc);
        }
        float hv = acc + ht[6][d * 33 + h] + bg;
        hv = hv > 0.f ? hv : 0.f;
        lmax = fmaxf(lmax, hv);
    }
    pmax[slot][h] = lmax;
    __syncthreads();

    // ---- Phase 3: pool-reduce + MLP + Q-select --------------------------
    if (t < 32) {
        float p = pmax[0][t];
        #pragma unroll
        for (int s2 = 1; s2 < 8; ++s2) p = fmaxf(p, pmax[s2][t]);
        cin[t] = p;
    } else if (t < 64) {
        const int k   = t - 32;
        const int jj  = k >> 4;                              // which "other"
        const int col = k & 15;
        const int other = (jj == 0) ? (a == 0 ? 1 : 0) : (a == 2 ? 1 : 2);
        cin[t] = actions[((size_t)other * Bq + b) * NACT + col];
    }
    __syncthreads();

    if (t < 32) {
        float acc = b1[a * Hh + t];
        #pragma unroll
        for (int k = 0; k < 64; ++k)
            acc = fmaf(cin[k], w1[((size_t)a * 64 + k) * Hh + t], acc);
        mid[t] = acc > 0.f ? acc : 0.01f * acc;
    }
    __syncthreads();

    if (t < 16) {
        float acc = b2[a * NACT + t];
        #pragma unroll
        for (int k = 0; k < 32; ++k)
            acc = fmaf(mid[k], w2[((size_t)a * Hh + k) * NACT + t], acc);
        allq[t] = acc;
    }
    __syncthreads();

    if (t == 0) {
        const float* act = actions + ((size_t)a * Bq + b) * NACT;
        int best = 0;
        float bv = act[0];
        #pragma unroll
        for (int j = 1; j < NACT; ++j) {
            float v = act[j];
            if (v > bv) { bv = v; best = j; }   // strict > = first-max (argmax)
        }
        out[(size_t)a * Bq + b] = allq[best];
    }
}

extern "C" void kernel_launch(void* const* d_in, const int* in_sizes, int n_in,
                              void* d_out, int out_size, void* d_ws, size_t ws_size,
                              hipStream_t stream) {
    const float* unary   = (const float*)d_in[0];
    const float* actions = (const float*)d_in[1];
    const float* w_rel   = (const float*)d_in[2];
    const float* w_root  = (const float*)d_in[3];
    const float* b_gnn   = (const float*)d_in[4];
    const float* w1      = (const float*)d_in[5];
    const float* b1      = (const float*)d_in[6];
    const float* b2      = (const float*)d_in[8];
    const float* w2      = (const float*)d_in[7];
    const int* edge_src  = (const int*)d_in[9];
    const int* edge_dst  = (const int*)d_in[10];
    const int* edge_rel  = (const int*)d_in[11];
    float* out = (float*)d_out;

    int*  row_start = (int*)d_ws;
    int2* entries   = (int2*)((char*)d_ws + 512);

    prep_edges<<<1, 256, 0, stream>>>(edge_src, edge_dst, edge_rel,
                                      row_start, entries);

    dim3 grid(Bq, A_AG);
    critic_kernel<<<grid, 256, 0, stream>>>(unary, actions, w_rel, w_root,
                                            b_gnn, w1, b1, w2, b2,
                                            row_start, entries, out);
}

// Round 2
// 319.653 us; speedup vs baseline: 3.7837x; 3.7837x over previous
//
#include <hip/hip_runtime.h>
#include <hip/hip_bf16.h>
#include <math.h>

// Problem constants (from reference)
#define A_AG   3
#define Bq     4096
#define Nn     64
#define FEAT   32
#define Hh     32
#define Rr     6
#define E_PER  1536
#define NACT   16

#define KCAT   224           // 6*32 relation slots + 32 root slot
#define XSTRIDE 232          // bf16 elems per xcat row (224 + 8 pad)

typedef __attribute__((ext_vector_type(8))) short          bfrag;   // MFMA A/B frag (8 bf16)
typedef __attribute__((ext_vector_type(4))) float          f32x4;   // MFMA C/D frag
typedef __attribute__((ext_vector_type(8))) unsigned short u16x8;

__device__ __forceinline__ ushort f2bf(float x) {        // RNE f32 -> bf16 bits
    unsigned u = __float_as_uint(x);
    u = (u + 0x7fffu + ((u >> 16) & 1u)) >> 16;
    return (ushort)u;
}
__device__ __forceinline__ float bf2f(ushort b) {
    return __uint_as_float(((unsigned)b) << 16);
}

// ---------------------------------------------------------------------------
// Kernel 1 (one block): shared across all (b,a):
//   - CSR of edges sorted by (dst, rel): rs2[385], entries[1536] (= src)
//   - invdeg[384] = 1/max(cnt(dst,rel),1)
//   - Wt bf16 [32][224]: Wt[h][r*32+f] = w_rel[r][f][h]; Wt[h][192+f] = w_root[f][h]
// Within-segment edge order is scrambled (atomic cursors) — sums are
// order-independent up to f32 rounding, fine for the threshold.
// ---------------------------------------------------------------------------
__global__ void prep(const float* __restrict__ w_rel,
                     const float* __restrict__ w_root,
                     const int* __restrict__ esrc,
                     const int* __restrict__ edst,
                     const int* __restrict__ erel,
                     int*    __restrict__ rs2_g,
                     float*  __restrict__ invdeg_g,
                     int*    __restrict__ entries_g,
                     ushort* __restrict__ Wt_g) {
    __shared__ int cnt[Nn * Rr];
    __shared__ int rs[Nn * Rr + 1];
    __shared__ int cur[Nn * Rr];
    const int t = threadIdx.x;

    for (int i = t; i < Nn * Rr; i += 256) cnt[i] = 0;
    __syncthreads();
    for (int e = t; e < E_PER; e += 256)
        atomicAdd(&cnt[edst[e] * Rr + erel[e]], 1);
    __syncthreads();
    if (t == 0) {
        int s = 0;
        for (int i = 0; i < Nn * Rr; ++i) { rs[i] = s; s += cnt[i]; }
        rs[Nn * Rr] = s;
    }
    __syncthreads();
    for (int i = t; i < Nn * Rr; i += 256) {
        cur[i] = rs[i];
        invdeg_g[i] = 1.0f / fmaxf((float)cnt[i], 1.0f);
    }
    for (int i = t; i < Nn * Rr + 1; i += 256) rs2_g[i] = rs[i];
    __syncthreads();
    for (int e = t; e < E_PER; e += 256) {
        const int seg = edst[e] * Rr + erel[e];
        const int pos = atomicAdd(&cur[seg], 1);
        entries_g[pos] = esrc[e];
    }
    // stacked transposed weights -> bf16
    for (int i = t; i < Hh * KCAT; i += 256) {
        const int h = i / KCAT, kk = i % KCAT;
        float v;
        if (kk < 192) v = w_rel[(((kk >> 5) * FEAT) + (kk & 31)) * Hh + h];
        else          v = w_root[(kk - 192) * Hh + h];
        Wt_g[i] = f2bf(v);
    }
}

// ---------------------------------------------------------------------------
// Kernel 2: one workgroup (256 thr) per (graph b, agent a).
//   P0: stage X (f32->bf16) into xcat root slot [*,192:224]
//   P1: edge aggregation in X-space: xcat[d, r*32:+32] = invdeg * sum X[src]
//       (thread = (dst, 8-feat group), rel loop statically unrolled)
//   P2: MFMA GEMM [64 x 224] @ [224 x 32] -> agg; +bias, ReLU, max-pool
//       (wave w owns 16-row tile; 2 n-tiles; 7 k-steps)
//   P3: pooled ++ other-actions -> 64->32 leaky -> 32->16 -> Q-select
// ---------------------------------------------------------------------------
__global__ __launch_bounds__(256) void critic_kernel(
    const float* __restrict__ unary,    // [A,B,N,FEAT]
    const float* __restrict__ actions,  // [A,B,NACT]
    const float* __restrict__ b_gnn,    // [H]
    const float* __restrict__ w1,       // [A,64,H]
    const float* __restrict__ b1,       // [A,H]
    const float* __restrict__ w2,       // [A,H,NACT]
    const float* __restrict__ b2,       // [A,NACT]
    const int*   __restrict__ rs2,      // [385]
    const float* __restrict__ invdeg,   // [384]
    const int*   __restrict__ entries,  // [1536] src, sorted by (dst,rel)
    const ushort* __restrict__ Wt,      // [32][224] bf16
    float* __restrict__ out)            // [A,B,1]
{
    const int b = blockIdx.x;
    const int a = blockIdx.y;
    const int t = threadIdx.x;

    __shared__ ushort xcat[Nn * XSTRIDE];   // 29696 B
    __shared__ float pmax[4][32];
    __shared__ float cin[64];
    __shared__ float mid[32];
    __shared__ float allq[16];

    // ---- P0: stage X into root slot --------------------------------------
    {
        const int row = t >> 2, f0 = (t & 3) * 8;
        const float* xp = unary + (((size_t)a * Bq + b) * Nn + row) * FEAT + f0;
        const float4 v0 = *(const float4*)xp;
        const float4 v1 = *(const float4*)(xp + 4);
        u16x8 pk;
        pk[0] = f2bf(v0.x); pk[1] = f2bf(v0.y); pk[2] = f2bf(v0.z); pk[3] = f2bf(v0.w);
        pk[4] = f2bf(v1.x); pk[5] = f2bf(v1.y); pk[6] = f2bf(v1.z); pk[7] = f2bf(v1.w);
        *(u16x8*)&xcat[row * XSTRIDE + 192 + f0] = pk;
    }
    __syncthreads();

    // ---- P1: edge aggregation (X-space) ----------------------------------
    {
        const int d = t >> 2, fg = t & 3;
        const int base = d * Rr;
        int e_next = rs2[base];
        #pragma unroll
        for (int r = 0; r < Rr; ++r) {
            const int e0 = e_next;
            const int e1 = rs2[base + r + 1];
            e_next = e1;
            float s0=0.f,s1=0.f,s2=0.f,s3=0.f,s4=0.f,s5=0.f,s6=0.f,s7=0.f;
            for (int e = e0; e < e1; ++e) {
                const int src = entries[e];
                const u16x8 v = *(const u16x8*)&xcat[src * XSTRIDE + 192 + fg * 8];
                s0 += bf2f(v[0]); s1 += bf2f(v[1]); s2 += bf2f(v[2]); s3 += bf2f(v[3]);
                s4 += bf2f(v[4]); s5 += bf2f(v[5]); s6 += bf2f(v[6]); s7 += bf2f(v[7]);
            }
            const float inv = invdeg[base + r];
            u16x8 pk;
            pk[0] = f2bf(s0 * inv); pk[1] = f2bf(s1 * inv);
            pk[2] = f2bf(s2 * inv); pk[3] = f2bf(s3 * inv);
            pk[4] = f2bf(s4 * inv); pk[5] = f2bf(s5 * inv);
            pk[6] = f2bf(s6 * inv); pk[7] = f2bf(s7 * inv);
            *(u16x8*)&xcat[d * XSTRIDE + r * 32 + fg * 8] = pk;
        }
    }
    __syncthreads();

    // ---- P2: MFMA GEMM + bias + ReLU + max-pool --------------------------
    {
        const int l  = t & 63, w = t >> 6;
        const int lr = l & 15, kg = l >> 4;
        const ushort* arow  = &xcat[(w * 16 + lr) * XSTRIDE + kg * 8];
        const ushort* bcol0 = Wt + lr * KCAT + kg * 8;
        const ushort* bcol1 = Wt + (16 + lr) * KCAT + kg * 8;
        f32x4 acc0 = {0.f, 0.f, 0.f, 0.f};
        f32x4 acc1 = {0.f, 0.f, 0.f, 0.f};
        #pragma unroll
        for (int ks = 0; ks < 7; ++ks) {
            const bfrag af = *(const bfrag*)(arow + ks * 32);
            const bfrag b0 = *(const bfrag*)(bcol0 + ks * 32);
            const bfrag b1 = *(const bfrag*)(bcol1 + ks * 32);
            acc0 = __builtin_amdgcn_mfma_f32_16x16x32_bf16(af, b0, acc0, 0, 0, 0);
            acc1 = __builtin_amdgcn_mfma_f32_16x16x32_bf16(af, b1, acc1, 0, 0, 0);
        }
        const float bg0 = b_gnn[lr], bg1 = b_gnn[16 + lr];
        float m0 = -INFINITY, m1 = -INFINITY;
        #pragma unroll
        for (int j = 0; j < 4; ++j) {
            m0 = fmaxf(m0, fmaxf(acc0[j] + bg0, 0.f));
            m1 = fmaxf(m1, fmaxf(acc1[j] + bg1, 0.f));
        }
        m0 = fmaxf(m0, __shfl_xor(m0, 16));
        m0 = fmaxf(m0, __shfl_xor(m0, 32));
        m1 = fmaxf(m1, __shfl_xor(m1, 16));
        m1 = fmaxf(m1, __shfl_xor(m1, 32));
        if (l < 16) { pmax[w][lr] = m0; pmax[w][16 + lr] = m1; }
    }
    __syncthreads();

    // ---- P3: pool-reduce + critic input + MLP + Q-select -----------------
    if (t < 32) {
        cin[t] = fmaxf(fmaxf(pmax[0][t], pmax[1][t]),
                       fmaxf(pmax[2][t], pmax[3][t]));
    } else if (t < 64) {
        const int k   = t - 32;
        const int jj  = k >> 4;
        const int col = k & 15;
        const int other = (jj == 0) ? (a == 0 ? 1 : 0) : (a == 2 ? 1 : 2);
        cin[t] = actions[((size_t)other * Bq + b) * NACT + col];
    }
    __syncthreads();

    if (t < 32) {
        float acc = b1[a * Hh + t];
        #pragma unroll
        for (int k = 0; k < 64; ++k)
            acc = fmaf(cin[k], w1[((size_t)a * 64 + k) * Hh + t], acc);
        mid[t] = acc > 0.f ? acc : 0.01f * acc;
    }
    __syncthreads();

    if (t < 16) {
        float acc = b2[a * NACT + t];
        #pragma unroll
        for (int k = 0; k < 32; ++k)
            acc = fmaf(mid[k], w2[((size_t)a * Hh + k) * NACT + t], acc);
        allq[t] = acc;
    }
    __syncthreads();

    if (t == 0) {
        const float* act = actions + ((size_t)a * Bq + b) * NACT;
        int best = 0;
        float bv = act[0];
        #pragma unroll
        for (int j = 1; j < NACT; ++j) {
            float v = act[j];
            if (v > bv) { bv = v; best = j; }   // strict > = first-max (argmax)
        }
        out[(size_t)a * Bq + b] = allq[best];
    }
}

extern "C" void kernel_launch(void* const* d_in, const int* in_sizes, int n_in,
                              void* d_out, int out_size, void* d_ws, size_t ws_size,
                              hipStream_t stream) {
    const float* unary   = (const float*)d_in[0];
    const float* actions = (const float*)d_in[1];
    const float* w_rel   = (const float*)d_in[2];
    const float* w_root  = (const float*)d_in[3];
    const float* b_gnn   = (const float*)d_in[4];
    const float* w1      = (const float*)d_in[5];
    const float* b1      = (const float*)d_in[6];
    const float* w2      = (const float*)d_in[7];
    const float* b2      = (const float*)d_in[8];
    const int* edge_src  = (const int*)d_in[9];
    const int* edge_dst  = (const int*)d_in[10];
    const int* edge_rel  = (const int*)d_in[11];
    float* out = (float*)d_out;

    // ws layout (all 16B-aligned blocks):
    //   [0,     2048)  rs2      (385 ints)
    //   [2048,  4096)  invdeg   (384 f32)
    //   [4096, 10240)  entries  (1536 ints)
    //   [10240,24576)  Wt       (32*224 bf16)
    char* ws = (char*)d_ws;
    int*    rs2_g     = (int*)(ws + 0);
    float*  invdeg_g  = (float*)(ws + 2048);
    int*    entries_g = (int*)(ws + 4096);
    ushort* Wt_g      = (ushort*)(ws + 10240);

    prep<<<1, 256, 0, stream>>>(w_rel, w_root, edge_src, edge_dst, edge_rel,
                                rs2_g, invdeg_g, entries_g, Wt_g);

    dim3 grid(Bq, A_AG);
    critic_kernel<<<grid, 256, 0, stream>>>(unary, actions, b_gnn,
                                            w1, b1, w2, b2,
                                            rs2_g, invdeg_g, entries_g, Wt_g,
                                            out);
}

// Round 3
// 302.389 us; speedup vs baseline: 3.9997x; 1.0571x over previous
//
#include <hip/hip_runtime.h>
#include <hip/hip_bf16.h>
#include <math.h>

// Problem constants
#define A_AG   3
#define Bq     4096
#define Nn     64
#define FEAT   32
#define Hh     32
#define Rr     6
#define E_PER  1536
#define NACT   16

#define KCAT    224          // 6*32 relation slots + 32 root slot
#define XSTRIDE 232          // xcat row stride in ushorts (29 granules of 16B, odd -> no conflicts)
#define TSTRIDE 72           // Xt row stride in ushorts (9 granules, odd)
#define NDR     384          // (dst, rel) rows in Adj
#define NEXT    448          // + 64 identity rows (root copy)

typedef __attribute__((ext_vector_type(8))) short          bfrag;   // MFMA A/B frag (8 bf16)
typedef __attribute__((ext_vector_type(4))) float          f32x4;   // MFMA C/D frag
typedef __attribute__((ext_vector_type(8))) unsigned short u16x8;

__device__ __forceinline__ ushort f2bf(float x) {        // RNE f32 -> bf16 bits
    unsigned u = __float_as_uint(x);
    u = (u + 0x7fffu + ((u >> 16) & 1u)) >> 16;
    return (ushort)u;
}
__device__ __forceinline__ float bf2f(ushort b) {
    return __uint_as_float(((unsigned)b) << 16);
}
__device__ __forceinline__ unsigned cvt_pk_bf16(float lo, float hi) {
    unsigned r;
    asm volatile("v_cvt_pk_bf16_f32 %0, %1, %2" : "=v"(r) : "v"(lo), "v"(hi));
    return r;
}

// ---------------------------------------------------------------------------
// Kernel 1 (one block, 1024 thr), all phases parallel (no serial scan):
//   - cnt[d,r] by atomics -> invdeg
//   - Adjf f32 [448][64] scratch: multiplicity scatter (+ identity rows)
//   - Adjbf bf16 [448][64] = Adjf * invdeg   (row >= 384 -> *1.0)
//   - Wt bf16 [32][224]: Wt[h][r*32+f] = w_rel[r][f][h]; Wt[h][192+f] = w_root[f][h]
// ---------------------------------------------------------------------------
__global__ __launch_bounds__(1024) void prep(
        const float* __restrict__ w_rel,
        const float* __restrict__ w_root,
        const int* __restrict__ esrc,
        const int* __restrict__ edst,
        const int* __restrict__ erel,
        float*  __restrict__ Adjf,      // [448*64] scratch
        ushort* __restrict__ Adjbf,     // [448*64]
        ushort* __restrict__ Wt_g) {    // [32*224]
    __shared__ int   cnt[NDR];
    __shared__ float invd[NEXT];
    const int t = threadIdx.x;

    for (int i = t; i < NDR; i += 1024) cnt[i] = 0;
    __syncthreads();
    for (int e = t; e < E_PER; e += 1024)
        atomicAdd(&cnt[edst[e] * Rr + erel[e]], 1);
    __syncthreads();
    for (int i = t; i < NEXT; i += 1024)
        invd[i] = (i < NDR) ? 1.0f / fmaxf((float)cnt[i], 1.0f) : 1.0f;
    for (int i = t; i < NEXT * Nn; i += 1024) Adjf[i] = 0.f;
    __syncthreads();
    for (int e = t; e < E_PER; e += 1024)
        atomicAdd(&Adjf[(edst[e] * Rr + erel[e]) * Nn + esrc[e]], 1.0f);
    if (t < Nn) Adjf[(NDR + t) * Nn + t] = 1.0f;   // identity rows (root copy)
    __syncthreads();
    for (int i = t; i < NEXT * Nn; i += 1024)
        Adjbf[i] = f2bf(Adjf[i] * invd[i >> 6]);
    for (int i = t; i < Hh * KCAT; i += 1024) {
        const int h = i / KCAT, kk = i % KCAT;
        float v;
        if (kk < 192) v = w_rel[(((kk >> 5) * FEAT) + (kk & 31)) * Hh + h];
        else          v = w_root[(kk - 192) * Hh + h];
        Wt_g[i] = f2bf(v);
    }
}

// ---------------------------------------------------------------------------
// Kernel 2: one workgroup (256 thr) per (graph b, agent a).
//   P0: stage X^T (f32->bf16) into Xt[32][72]  (column loads, coalesced)
//   P1: GEMM1 via MFMA: D[f][dr] = X^T @ Adj^T  (M=32,N=448,K=64)
//       -> writes all of xcat (relation slots + root copy via identity rows)
//   P2: GEMM2 via MFMA: [64 x 224] @ [224 x 32], +bias, ReLU, max-pool
//   P3: pooled ++ other-actions -> 64->32 leaky -> 32->16 -> Q-select
// ---------------------------------------------------------------------------
__global__ __launch_bounds__(256, 4) void critic_kernel(
    const float* __restrict__ unary,    // [A,B,N,FEAT]
    const float* __restrict__ actions,  // [A,B,NACT]
    const float* __restrict__ b_gnn,    // [H]
    const float* __restrict__ w1,       // [A,64,H]
    const float* __restrict__ b1,       // [A,H]
    const float* __restrict__ w2,       // [A,H,NACT]
    const float* __restrict__ b2,       // [A,NACT]
    const ushort* __restrict__ Adj,     // [448][64] bf16 (shared, L2-hot)
    const ushort* __restrict__ Wt,      // [32][224] bf16
    float* __restrict__ out)            // [A,B,1]
{
    const int b = blockIdx.x;
    const int a = blockIdx.y;
    const int t = threadIdx.x;

    __shared__ ushort Xt[FEAT * TSTRIDE];   // 4608 B, X transposed
    __shared__ ushort xcat[Nn * XSTRIDE];   // 29696 B
    __shared__ float pmax[4][32];
    __shared__ float cin[64];
    __shared__ float mid[32];
    __shared__ float allq[16];

    // ---- P0: stage X^T ---------------------------------------------------
    {
        const int f = t & 31, sg = t >> 5;         // feature col, 8-row group
        const float* xp = unary + ((((size_t)a * Bq + b) * Nn + sg * 8) * FEAT) + f;
        unsigned w0 = cvt_pk_bf16(xp[0 * FEAT], xp[1 * FEAT]);
        unsigned w1_ = cvt_pk_bf16(xp[2 * FEAT], xp[3 * FEAT]);
        unsigned w2_ = cvt_pk_bf16(xp[4 * FEAT], xp[5 * FEAT]);
        unsigned w3 = cvt_pk_bf16(xp[6 * FEAT], xp[7 * FEAT]);
        uint4 v = {w0, w1_, w2_, w3};
        *(uint4*)&Xt[f * TSTRIDE + sg * 8] = v;
    }
    __syncthreads();

    // ---- P1: GEMM1 (aggregation as dense MFMA) ---------------------------
    {
        const int l = t & 63, w = t >> 6;
        const int lr = l & 15, kg = l >> 4;

        bfrag af[2][2];
        #pragma unroll
        for (int mt = 0; mt < 2; ++mt)
            #pragma unroll
            for (int ks = 0; ks < 2; ++ks)
                af[mt][ks] = *(const bfrag*)&Xt[(mt * 16 + lr) * TSTRIDE + ks * 32 + kg * 8];

        const ushort* abase = Adj + (size_t)(w * 7 * 16 + lr) * Nn + kg * 8;
        f32x4 acc[7][2];
        #pragma unroll
        for (int i = 0; i < 7; ++i) {
            acc[i][0] = (f32x4){0.f, 0.f, 0.f, 0.f};
            acc[i][1] = (f32x4){0.f, 0.f, 0.f, 0.f};
        }
        #pragma unroll
        for (int i = 0; i < 7; ++i) {
            const bfrag b0 = *(const bfrag*)(abase + i * 16 * Nn);
            const bfrag b1f = *(const bfrag*)(abase + i * 16 * Nn + 32);
            acc[i][0] = __builtin_amdgcn_mfma_f32_16x16x32_bf16(af[0][0], b0,  acc[i][0], 0, 0, 0);
            acc[i][1] = __builtin_amdgcn_mfma_f32_16x16x32_bf16(af[1][0], b0,  acc[i][1], 0, 0, 0);
            acc[i][0] = __builtin_amdgcn_mfma_f32_16x16x32_bf16(af[0][1], b1f, acc[i][0], 0, 0, 0);
            acc[i][1] = __builtin_amdgcn_mfma_f32_16x16x32_bf16(af[1][1], b1f, acc[i][1], 0, 0, 0);
        }
        // epilogue: scatter D[f][dr] -> xcat[d][r*32+f] (or root slot)
        #pragma unroll
        for (int i = 0; i < 7; ++i) {
            const int nt = w * 7 + i;
            const int dr = nt * 16 + lr;
            int row, colb;
            if (nt < 24) {                       // wave-uniform branch
                const int d = (dr * 10923) >> 16;
                const int r = dr - 6 * d;
                row = d; colb = r * 32;
            } else {
                row = dr - NDR; colb = 192;
            }
            #pragma unroll
            for (int mt = 0; mt < 2; ++mt) {
                const unsigned lo = cvt_pk_bf16(acc[i][mt][0], acc[i][mt][1]);
                const unsigned hi = cvt_pk_bf16(acc[i][mt][2], acc[i][mt][3]);
                uint2 v = {lo, hi};
                *(uint2*)&xcat[row * XSTRIDE + colb + mt * 16 + kg * 4] = v;
            }
        }
    }
    __syncthreads();

    // ---- P2: GEMM2 + bias + ReLU + max-pool ------------------------------
    {
        const int l = t & 63, w = t >> 6;
        const int lr = l & 15, kg = l >> 4;
        const ushort* arow  = &xcat[(w * 16 + lr) * XSTRIDE + kg * 8];
        const ushort* bcol0 = Wt + lr * KCAT + kg * 8;
        const ushort* bcol1 = Wt + (16 + lr) * KCAT + kg * 8;
        f32x4 acc0 = {0.f, 0.f, 0.f, 0.f};
        f32x4 acc1 = {0.f, 0.f, 0.f, 0.f};
        #pragma unroll
        for (int ks = 0; ks < 7; ++ks) {
            const bfrag afr = *(const bfrag*)(arow + ks * 32);
            const bfrag b0  = *(const bfrag*)(bcol0 + ks * 32);
            const bfrag b1  = *(const bfrag*)(bcol1 + ks * 32);
            acc0 = __builtin_amdgcn_mfma_f32_16x16x32_bf16(afr, b0, acc0, 0, 0, 0);
            acc1 = __builtin_amdgcn_mfma_f32_16x16x32_bf16(afr, b1, acc1, 0, 0, 0);
        }
        const float bg0 = b_gnn[lr], bg1 = b_gnn[16 + lr];
        float m0 = -INFINITY, m1 = -INFINITY;
        #pragma unroll
        for (int j = 0; j < 4; ++j) {
            m0 = fmaxf(m0, fmaxf(acc0[j] + bg0, 0.f));
            m1 = fmaxf(m1, fmaxf(acc1[j] + bg1, 0.f));
        }
        m0 = fmaxf(m0, __shfl_xor(m0, 16));
        m0 = fmaxf(m0, __shfl_xor(m0, 32));
        m1 = fmaxf(m1, __shfl_xor(m1, 16));
        m1 = fmaxf(m1, __shfl_xor(m1, 32));
        if (l < 16) { pmax[w][lr] = m0; pmax[w][16 + lr] = m1; }
    }
    __syncthreads();

    // ---- P3: pool-reduce + critic input + MLP + Q-select -----------------
    if (t < 32) {
        cin[t] = fmaxf(fmaxf(pmax[0][t], pmax[1][t]),
                       fmaxf(pmax[2][t], pmax[3][t]));
    } else if (t < 64) {
        const int k   = t - 32;
        const int jj  = k >> 4;
        const int col = k & 15;
        const int other = (jj == 0) ? (a == 0 ? 1 : 0) : (a == 2 ? 1 : 2);
        cin[t] = actions[((size_t)other * Bq + b) * NACT + col];
    }
    __syncthreads();

    if (t < 32) {
        float acc = b1[a * Hh + t];
        #pragma unroll
        for (int k = 0; k < 64; ++k)
            acc = fmaf(cin[k], w1[((size_t)a * 64 + k) * Hh + t], acc);
        mid[t] = acc > 0.f ? acc : 0.01f * acc;
    }
    __syncthreads();

    if (t < 16) {
        float acc = b2[a * NACT + t];
        #pragma unroll
        for (int k = 0; k < 32; ++k)
            acc = fmaf(mid[k], w2[((size_t)a * Hh + k) * NACT + t], acc);
        allq[t] = acc;
    }
    __syncthreads();

    if (t == 0) {
        const float* act = actions + ((size_t)a * Bq + b) * NACT;
        int best = 0;
        float bv = act[0];
        #pragma unroll
        for (int j = 1; j < NACT; ++j) {
            float v = act[j];
            if (v > bv) { bv = v; best = j; }   // strict > = first-max (argmax)
        }
        out[(size_t)a * Bq + b] = allq[best];
    }
}

extern "C" void kernel_launch(void* const* d_in, const int* in_sizes, int n_in,
                              void* d_out, int out_size, void* d_ws, size_t ws_size,
                              hipStream_t stream) {
    const float* unary   = (const float*)d_in[0];
    const float* actions = (const float*)d_in[1];
    const float* w_rel   = (const float*)d_in[2];
    const float* w_root  = (const float*)d_in[3];
    const float* b_gnn   = (const float*)d_in[4];
    const float* w1      = (const float*)d_in[5];
    const float* b1      = (const float*)d_in[6];
    const float* w2      = (const float*)d_in[7];
    const float* b2      = (const float*)d_in[8];
    const int* edge_src  = (const int*)d_in[9];
    const int* edge_dst  = (const int*)d_in[10];
    const int* edge_rel  = (const int*)d_in[11];
    float* out = (float*)d_out;

    // ws layout (256B-aligned):
    //   [0,      57344)  Adjbf  (448*64 bf16)
    //   [57344,  71680)  Wt     (32*224 bf16)
    //   [71680, 186368)  Adjf   (448*64 f32 scratch)
    char* ws = (char*)d_ws;
    ushort* Adjbf = (ushort*)(ws + 0);
    ushort* Wt_g  = (ushort*)(ws + 57344);
    float*  Adjf  = (float*)(ws + 71680);

    prep<<<1, 1024, 0, stream>>>(w_rel, w_root, edge_src, edge_dst, edge_rel,
                                 Adjf, Adjbf, Wt_g);

    dim3 grid(Bq, A_AG);
    critic_kernel<<<grid, 256, 0, stream>>>(unary, actions, b_gnn,
                                            w1, b1, w2, b2,
                                            Adjbf, Wt_g, out);
}

// Round 13
// 289.496 us; speedup vs baseline: 4.1778x; 1.0445x over previous
//
#include <hip/hip_runtime.h>
#include <hip/hip_bf16.h>
#include <math.h>

// Problem constants
#define A_AG   3
#define Bq     4096
#define Nn     64
#define FEAT   32
#define Hh     32
#define Rr     6
#define E_PER  1536
#define NACT   16

#define KCAT    224          // 6*32 relation slots + 32 root slot
#define XSTRIDE 232          // xcat row stride (ushorts) — odd 16B-granule count
#define TSTRIDE 72           // Xt row stride (ushorts)
#define NDR     384          // (dst, rel) rows in Adj
#define NEXT    448          // + 64 identity rows (root copy)
#define GT      8            // graphs per tail block

typedef __attribute__((ext_vector_type(8))) short          bfrag;   // MFMA A/B frag (8 bf16)
typedef __attribute__((ext_vector_type(4))) float          f32x4;   // MFMA C/D frag

__device__ __forceinline__ ushort f2bf(float x) {        // RNE f32 -> bf16 bits
    unsigned u = __float_as_uint(x);
    u = (u + 0x7fffu + ((u >> 16) & 1u)) >> 16;
    return (ushort)u;
}
__device__ __forceinline__ unsigned cvt_pk_bf16(float lo, float hi) {
    unsigned r;
    asm volatile("v_cvt_pk_bf16_f32 %0, %1, %2" : "=v"(r) : "v"(lo), "v"(hi));
    return r;
}

// ---------------------------------------------------------------------------
// Kernel 1 (one block, 1024 thr) — byte-identical to R3 (passed):
//   Adjbf bf16 [448][64] = (multiplicity * invdeg | identity), Wt bf16 [32][224]
// ---------------------------------------------------------------------------
__global__ __launch_bounds__(1024) void prep(
        const float* __restrict__ w_rel,
        const float* __restrict__ w_root,
        const int* __restrict__ esrc,
        const int* __restrict__ edst,
        const int* __restrict__ erel,
        float*  __restrict__ Adjf,      // [448*64] scratch
        ushort* __restrict__ Adjbf,     // [448*64]
        ushort* __restrict__ Wt_g) {    // [32*224]
    __shared__ int   cnt[NDR];
    __shared__ float invd[NEXT];
    const int t = threadIdx.x;

    for (int i = t; i < NDR; i += 1024) cnt[i] = 0;
    __syncthreads();
    for (int e = t; e < E_PER; e += 1024)
        atomicAdd(&cnt[edst[e] * Rr + erel[e]], 1);
    __syncthreads();
    for (int i = t; i < NEXT; i += 1024)
        invd[i] = (i < NDR) ? 1.0f / fmaxf((float)cnt[i], 1.0f) : 1.0f;
    for (int i = t; i < NEXT * Nn; i += 1024) Adjf[i] = 0.f;
    __syncthreads();
    for (int e = t; e < E_PER; e += 1024)
        atomicAdd(&Adjf[(edst[e] * Rr + erel[e]) * Nn + esrc[e]], 1.0f);
    if (t < Nn) Adjf[(NDR + t) * Nn + t] = 1.0f;   // identity rows (root copy)
    __syncthreads();
    for (int i = t; i < NEXT * Nn; i += 1024)
        Adjbf[i] = f2bf(Adjf[i] * invd[i >> 6]);
    for (int i = t; i < Hh * KCAT; i += 1024) {
        const int h = i / KCAT, kk = i % KCAT;
        float v;
        if (kk < 192) v = w_rel[(((kk >> 5) * FEAT) + (kk & 31)) * Hh + h];
        else          v = w_root[(kk - 192) * Hh + h];
        Wt_g[i] = f2bf(v);
    }
}

// ---------------------------------------------------------------------------
// Kernel 2: EXACT R3 critic body (passed), one (b,a) per block, with P3
// replaced by a 32-float pooled write to global ws. No g-loop.
// ---------------------------------------------------------------------------
__global__ __launch_bounds__(256, 4) void critic_kernel(
    const float* __restrict__ unary,    // [A,B,N,FEAT]
    const float* __restrict__ b_gnn,    // [H]
    const ushort* __restrict__ Adj,     // [448][64] bf16 (shared, L2-hot)
    const ushort* __restrict__ Wt,      // [32][224] bf16
    float* __restrict__ pooled_g)       // [A,B,32]
{
    const int b = blockIdx.x;
    const int a = blockIdx.y;
    const int t = threadIdx.x;

    __shared__ ushort Xt[FEAT * TSTRIDE];   // 4608 B
    __shared__ ushort xcat[Nn * XSTRIDE];   // 29696 B
    __shared__ float pmax[4][32];

    // ---- P0: stage X^T (exact R3 code) -----------------------------------
    {
        const int f = t & 31, sg = t >> 5;
        const float* xp = unary + ((((size_t)a * Bq + b) * Nn + sg * 8) * FEAT) + f;
        unsigned w0 = cvt_pk_bf16(xp[0 * FEAT], xp[1 * FEAT]);
        unsigned w1_ = cvt_pk_bf16(xp[2 * FEAT], xp[3 * FEAT]);
        unsigned w2_ = cvt_pk_bf16(xp[4 * FEAT], xp[5 * FEAT]);
        unsigned w3 = cvt_pk_bf16(xp[6 * FEAT], xp[7 * FEAT]);
        uint4 v = {w0, w1_, w2_, w3};
        *(uint4*)&Xt[f * TSTRIDE + sg * 8] = v;
    }
    __syncthreads();

    // ---- P1: GEMM1 (exact R3 code) ---------------------------------------
    {
        const int l = t & 63, w = t >> 6;
        const int lr = l & 15, kg = l >> 4;

        bfrag af[2][2];
        #pragma unroll
        for (int mt = 0; mt < 2; ++mt)
            #pragma unroll
            for (int ks = 0; ks < 2; ++ks)
                af[mt][ks] = *(const bfrag*)&Xt[(mt * 16 + lr) * TSTRIDE + ks * 32 + kg * 8];

        const ushort* abase = Adj + (size_t)(w * 7 * 16 + lr) * Nn + kg * 8;
        f32x4 acc[7][2];
        #pragma unroll
        for (int i = 0; i < 7; ++i) {
            acc[i][0] = (f32x4){0.f, 0.f, 0.f, 0.f};
            acc[i][1] = (f32x4){0.f, 0.f, 0.f, 0.f};
        }
        #pragma unroll
        for (int i = 0; i < 7; ++i) {
            const bfrag bb0 = *(const bfrag*)(abase + i * 16 * Nn);
            const bfrag bb1 = *(const bfrag*)(abase + i * 16 * Nn + 32);
            acc[i][0] = __builtin_amdgcn_mfma_f32_16x16x32_bf16(af[0][0], bb0, acc[i][0], 0, 0, 0);
            acc[i][1] = __builtin_amdgcn_mfma_f32_16x16x32_bf16(af[1][0], bb0, acc[i][1], 0, 0, 0);
            acc[i][0] = __builtin_amdgcn_mfma_f32_16x16x32_bf16(af[0][1], bb1, acc[i][0], 0, 0, 0);
            acc[i][1] = __builtin_amdgcn_mfma_f32_16x16x32_bf16(af[1][1], bb1, acc[i][1], 0, 0, 0);
        }
        #pragma unroll
        for (int i = 0; i < 7; ++i) {
            const int nt = w * 7 + i;
            const int dr = nt * 16 + lr;
            int row, colb;
            if (nt < 24) {
                const int d = (dr * 10923) >> 16;
                const int r = dr - 6 * d;
                row = d; colb = r * 32;
            } else {
                row = dr - NDR; colb = 192;
            }
            #pragma unroll
            for (int mt = 0; mt < 2; ++mt) {
                const unsigned lo = cvt_pk_bf16(acc[i][mt][0], acc[i][mt][1]);
                const unsigned hi = cvt_pk_bf16(acc[i][mt][2], acc[i][mt][3]);
                uint2 v = {lo, hi};
                *(uint2*)&xcat[row * XSTRIDE + colb + mt * 16 + kg * 4] = v;
            }
        }
    }
    __syncthreads();

    // ---- P2: GEMM2 + bias + ReLU + max (exact R3 code) -------------------
    {
        const int l = t & 63, w = t >> 6;
        const int lr = l & 15, kg = l >> 4;
        const ushort* arow  = &xcat[(w * 16 + lr) * XSTRIDE + kg * 8];
        const ushort* bcol0 = Wt + lr * KCAT + kg * 8;
        const ushort* bcol1 = Wt + (16 + lr) * KCAT + kg * 8;
        f32x4 acc0 = {0.f, 0.f, 0.f, 0.f};
        f32x4 acc1 = {0.f, 0.f, 0.f, 0.f};
        #pragma unroll
        for (int ks = 0; ks < 7; ++ks) {
            const bfrag afr = *(const bfrag*)(arow + ks * 32);
            const bfrag bf0 = *(const bfrag*)(bcol0 + ks * 32);
            const bfrag bf1 = *(const bfrag*)(bcol1 + ks * 32);
            acc0 = __builtin_amdgcn_mfma_f32_16x16x32_bf16(afr, bf0, acc0, 0, 0, 0);
            acc1 = __builtin_amdgcn_mfma_f32_16x16x32_bf16(afr, bf1, acc1, 0, 0, 0);
        }
        const float bg0 = b_gnn[lr], bg1 = b_gnn[16 + lr];
        float m0 = -INFINITY, m1 = -INFINITY;
        #pragma unroll
        for (int j = 0; j < 4; ++j) {
            m0 = fmaxf(m0, fmaxf(acc0[j] + bg0, 0.f));
            m1 = fmaxf(m1, fmaxf(acc1[j] + bg1, 0.f));
        }
        m0 = fmaxf(m0, __shfl_xor(m0, 16));
        m0 = fmaxf(m0, __shfl_xor(m0, 32));
        m1 = fmaxf(m1, __shfl_xor(m1, 16));
        m1 = fmaxf(m1, __shfl_xor(m1, 32));
        if (l < 16) { pmax[w][lr] = m0; pmax[w][16 + lr] = m1; }
    }
    __syncthreads();

    // ---- P3': pool-reduce -> global pooled (replaces R3 tail) ------------
    if (t < 32) {
        const float p = fmaxf(fmaxf(pmax[0][t], pmax[1][t]),
                              fmaxf(pmax[2][t], pmax[3][t]));
        pooled_g[((size_t)a * Bq + b) * Hh + t] = p;
    }
}

// ---------------------------------------------------------------------------
// Kernel 3: standalone MLP tail. Block = (8 graphs, agent a); weights staged
// in LDS once; mid/allq/select phases fully parallel. No g-loop anywhere.
// ---------------------------------------------------------------------------
__global__ __launch_bounds__(256) void tail_kernel(
    const float* __restrict__ pooled_g, // [A,B,32]
    const float* __restrict__ actions,  // [A,B,NACT]
    const float* __restrict__ w1,       // [A,64,H]
    const float* __restrict__ b1,       // [A,H]
    const float* __restrict__ w2,       // [A,H,NACT]
    const float* __restrict__ b2,       // [A,NACT]
    float* __restrict__ out)            // [A,B,1]
{
    const int b0 = blockIdx.x * GT;
    const int a  = blockIdx.y;
    const int t  = threadIdx.x;

    __shared__ float w1s[64][32];
    __shared__ float w2s[32][16];
    __shared__ float b1s[32];
    __shared__ float b2s[16];
    __shared__ float pl[GT][32];
    __shared__ float acts[GT][48];     // 0:16 own | 16:48 others
    __shared__ float mids[GT][32];
    __shared__ float allq[GT][16];

    // stage weights + inputs
    for (int i = t; i < 64 * 32; i += 256)
        w1s[i >> 5][i & 31] = w1[(size_t)a * 2048 + i];
    for (int i = t; i < 32 * 16; i += 256)
        w2s[i >> 4][i & 15] = w2[(size_t)a * 512 + i];
    if (t < 32) b1s[t] = b1[a * Hh + t];
    else if (t < 48) b2s[t - 32] = b2[a * NACT + (t - 32)];
    {
        const int g = t >> 5, h = t & 31;   // 256 thr = 8 g x 32 h, coalesced
        pl[g][h] = pooled_g[((size_t)a * Bq + b0 + g) * Hh + h];
    }
    for (int i = t; i < GT * 48; i += 256) {
        const int g = i / 48, j = i - g * 48;
        int src_a, col;
        if (j < 16)      { src_a = a;                 col = j; }
        else if (j < 32) { src_a = (a == 0 ? 1 : 0);  col = j - 16; }
        else             { src_a = (a == 2 ? 1 : 2);  col = j - 32; }
        acts[g][j] = actions[((size_t)src_a * Bq + b0 + g) * NACT + col];
    }
    __syncthreads();

    // mid = leaky_relu(cin @ w1 + b1): 256 thr = 8 g x 32 h
    {
        const int g = t >> 5, h = t & 31;
        float acc = b1s[h];
        #pragma unroll
        for (int k = 0; k < 32; ++k)
            acc = fmaf(pl[g][k], w1s[k][h], acc);
        #pragma unroll
        for (int k = 0; k < 32; ++k)
            acc = fmaf(acts[g][16 + k], w1s[32 + k][h], acc);
        mids[g][h] = acc > 0.f ? acc : 0.01f * acc;
    }
    __syncthreads();

    // allq = mid @ w2 + b2: 128 thr = 8 g x 16 q
    if (t < 128) {
        const int g = t >> 4, q = t & 15;
        float acc = b2s[q];
        #pragma unroll
        for (int k = 0; k < 32; ++k)
            acc = fmaf(mids[g][k], w2s[k][q], acc);
        allq[g][q] = acc;
    }
    __syncthreads();

    // Q-select by argmax(own actions), first-max semantics
    if (t < GT) {
        int best = 0;
        float bv = acts[t][0];
        #pragma unroll
        for (int j = 1; j < NACT; ++j) {
            const float v = acts[t][j];
            if (v > bv) { bv = v; best = j; }
        }
        out[(size_t)a * Bq + b0 + t] = allq[t][best];
    }
}

extern "C" void kernel_launch(void* const* d_in, const int* in_sizes, int n_in,
                              void* d_out, int out_size, void* d_ws, size_t ws_size,
                              hipStream_t stream) {
    const float* unary   = (const float*)d_in[0];
    const float* actions = (const float*)d_in[1];
    const float* w_rel   = (const float*)d_in[2];
    const float* w_root  = (const float*)d_in[3];
    const float* b_gnn   = (const float*)d_in[4];
    const float* w1      = (const float*)d_in[5];
    const float* b1      = (const float*)d_in[6];
    const float* w2      = (const float*)d_in[7];
    const float* b2      = (const float*)d_in[8];
    const int* edge_src  = (const int*)d_in[9];
    const int* edge_dst  = (const int*)d_in[10];
    const int* edge_rel  = (const int*)d_in[11];
    float* out = (float*)d_out;

    // ws layout (256B-aligned):
    //   [0,       1572864)  pooled  (3*4096*32 f32)
    //   [1572864, 1630208)  Adjbf   (448*64 bf16)
    //   [1630208, 1644544)  Wt      (32*224 bf16)
    //   [1644544, 1759232)  Adjf    (448*64 f32 scratch)
    char* ws = (char*)d_ws;
    float*  pooled_g = (float*)(ws + 0);
    ushort* Adjbf    = (ushort*)(ws + 1572864);
    ushort* Wt_g     = (ushort*)(ws + 1630208);
    float*  Adjf     = (float*)(ws + 1644544);

    prep<<<1, 1024, 0, stream>>>(w_rel, w_root, edge_src, edge_dst, edge_rel,
                                 Adjf, Adjbf, Wt_g);

    dim3 grid(Bq, A_AG);
    critic_kernel<<<grid, 256, 0, stream>>>(unary, b_gnn, Adjbf, Wt_g, pooled_g);

    dim3 tgrid(Bq / GT, A_AG);
    tail_kernel<<<tgrid, 256, 0, stream>>>(pooled_g, actions, w1, b1, w2, b2, out);
}